// Round 1
// baseline (37.103 us; speedup 1.0000x reference)
//
#include <hip/hip_runtime.h>
#include <hip/hip_bf16.h>
#include <math.h>

#define SEQ_LEN 32768
#define HID 1024

// ---------------------------------------------------------------------------
// K1: v = W^T h.  W is [H,H] row-major (W[d,h] at W[d*H+h]); v[h] = sum_d h[d]*W[d,h].
// 32 blocks; block b owns columns [b*32, b*32+32). 256 threads = 32 cols x 8 d-slices
// of 128 each. No atomics, no memset needed.
// ---------------------------------------------------------------------------
__global__ void __launch_bounds__(256) k_matvec(const float* __restrict__ W,
                                                const float* __restrict__ hvec,
                                                float* __restrict__ v) {
    __shared__ float red[256];
    const int t = threadIdx.x;
    const int col = (blockIdx.x << 5) + (t & 31);
    const int slice = t >> 5;               // 0..7
    const int d0 = slice << 7;              // slice * 128
    float acc = 0.f;
#pragma unroll 8
    for (int dd = 0; dd < 128; ++dd) {
        const int d = d0 + dd;
        acc += hvec[d] * W[d * HID + col];
    }
    red[t] = acc;
    __syncthreads();
    if (t < 32) {
        float s = 0.f;
#pragma unroll
        for (int i = 0; i < 8; ++i) s += red[(i << 5) + t];
        v[(blockIdx.x << 5) + t] = s;
    }
}

// ---------------------------------------------------------------------------
// K2: energies[s] = enc[s,:] . v   (the HBM-bound 128 MB pass)
// 1024 blocks x 256 threads (4 waves). Each wave handles 8 rows.
// Per row: 64 lanes x 4 float4 = the full 1024-float row, coalesced.
// Online softmax stats (m, z) per block -> bstats[blockIdx].
// ---------------------------------------------------------------------------
__global__ void __launch_bounds__(256) k_energy(const float* __restrict__ enc,
                                                const float* __restrict__ v,
                                                float* __restrict__ energies,
                                                float2* __restrict__ bstats) {
    const int t = threadIdx.x;
    const int wave = t >> 6;
    const int lane = t & 63;
    const int row0 = (blockIdx.x << 5) + (wave << 3);

    // v fragment in registers (v is tiny and L2-hot)
    const float4 vr0 = *reinterpret_cast<const float4*>(v +       (lane << 2));
    const float4 vr1 = *reinterpret_cast<const float4*>(v + 256 + (lane << 2));
    const float4 vr2 = *reinterpret_cast<const float4*>(v + 512 + (lane << 2));
    const float4 vr3 = *reinterpret_cast<const float4*>(v + 768 + (lane << 2));

    float m = -__builtin_inff();
    float z = 0.f;

#pragma unroll 2
    for (int r = 0; r < 8; ++r) {
        const size_t row = (size_t)(row0 + r);
        const float4* p = reinterpret_cast<const float4*>(enc + row * HID) + lane;
        const float4 a = p[0];
        const float4 b = p[64];
        const float4 c = p[128];
        const float4 d = p[192];
        float acc = a.x * vr0.x + a.y * vr0.y + a.z * vr0.z + a.w * vr0.w
                  + b.x * vr1.x + b.y * vr1.y + b.z * vr1.z + b.w * vr1.w
                  + c.x * vr2.x + c.y * vr2.y + c.z * vr2.z + c.w * vr2.w
                  + d.x * vr3.x + d.y * vr3.y + d.z * vr3.z + d.w * vr3.w;
        // full 64-lane butterfly reduce
#pragma unroll
        for (int off = 32; off; off >>= 1) acc += __shfl_xor(acc, off, 64);
        if (lane == 0) energies[row] = acc;
        // online (m, z) update — identical value in all lanes
        const float nm = fmaxf(m, acc);
        z = z * __expf(m - nm) + __expf(acc - nm);
        m = nm;
    }

    __shared__ float wm[4], wz[4];
    if (lane == 0) { wm[wave] = m; wz[wave] = z; }
    __syncthreads();
    if (t == 0) {
        float M = fmaxf(fmaxf(wm[0], wm[1]), fmaxf(wm[2], wm[3]));
        float Z = wz[0] * __expf(wm[0] - M) + wz[1] * __expf(wm[1] - M)
                + wz[2] * __expf(wm[2] - M) + wz[3] * __expf(wm[3] - M);
        bstats[blockIdx.x] = make_float2(M, Z);
    }
}

// ---------------------------------------------------------------------------
// K3: reduce 1024 block stats -> (M, Z) (done redundantly per block; 8 KB L2 read),
// then write attn[i] = exp(e[i]-M)/Z. 64 blocks x 256 threads x 2 floats = 32768.
// ---------------------------------------------------------------------------
__global__ void __launch_bounds__(256) k_final(const float* __restrict__ energies,
                                               const float2* __restrict__ bstats,
                                               float* __restrict__ out) {
    __shared__ float sm[256], sz[256];
    const int t = threadIdx.x;
    float m = -__builtin_inff();
    float z = 0.f;
#pragma unroll
    for (int i = 0; i < 4; ++i) {
        const float2 s = bstats[t + (i << 8)];
        const float nm = fmaxf(m, s.x);
        z = z * __expf(m - nm) + s.y * __expf(s.x - nm);
        m = nm;
    }
    sm[t] = m; sz[t] = z;
    __syncthreads();
    for (int off = 128; off; off >>= 1) {
        if (t < off) {
            const float m1 = sm[t], z1 = sz[t];
            const float m2 = sm[t + off], z2 = sz[t + off];
            const float M = fmaxf(m1, m2);
            sm[t] = M;
            sz[t] = z1 * __expf(m1 - M) + z2 * __expf(m2 - M);
        }
        __syncthreads();
    }
    const float M = sm[0];
    const float rZ = 1.f / sz[0];

    const size_t i = ((size_t)blockIdx.x << 9) + ((size_t)t << 1);
    const float2 e = *reinterpret_cast<const float2*>(energies + i);
    float2 o;
    o.x = __expf(e.x - M) * rZ;
    o.y = __expf(e.y - M) * rZ;
    *reinterpret_cast<float2*>(out + i) = o;
}

extern "C" void kernel_launch(void* const* d_in, const int* in_sizes, int n_in,
                              void* d_out, int out_size, void* d_ws, size_t ws_size,
                              hipStream_t stream) {
    const float* hidden = (const float*)d_in[0];   // [1,1,1024]
    const float* enc    = (const float*)d_in[1];   // [32768,1024]
    const float* W      = (const float*)d_in[2];   // [1024,1024]
    // d_in[3] (bias) is mathematically irrelevant: b.h is constant across s,
    // and softmax is shift-invariant.

    float* ws       = (float*)d_ws;
    float* v        = ws;                          // 1024 floats
    float* energies = ws + HID;                    // 32768 floats
    float2* bstats  = (float2*)(ws + HID + SEQ_LEN); // 1024 float2

    k_matvec<<<HID / 32, 256, 0, stream>>>(W, hidden, v);
    k_energy<<<SEQ_LEN / 32, 256, 0, stream>>>(enc, v, energies, bstats);
    k_final<<<SEQ_LEN / 512, 256, 0, stream>>>(energies, bstats, (float*)d_out);
}

// Round 2
// 36.997 us; speedup vs baseline: 1.0029x; 1.0029x over previous
//
#include <hip/hip_runtime.h>
#include <hip/hip_bf16.h>
#include <math.h>

#define SEQ_LEN 32768
#define HID 1024

// ---------------------------------------------------------------------------
// K1: v = W^T h.  v[col] = sum_d hvec[d] * W[d*H + col].
// One block per column (1024 blocks, full-chip parallelism), 256 threads,
// 4 loads/thread, wave shfl reduce + tiny LDS combine. Deterministic.
// W lines are shared across adjacent-column blocks via L2/L3.
// ---------------------------------------------------------------------------
__global__ void __launch_bounds__(256) k_matvec(const float* __restrict__ W,
                                                const float* __restrict__ hvec,
                                                float* __restrict__ v) {
    const int col = blockIdx.x;
    const int t = threadIdx.x;
    float acc = 0.f;
#pragma unroll
    for (int i = 0; i < 4; ++i) {
        const int d = (i << 8) + t;
        acc = fmaf(hvec[d], W[d * HID + col], acc);
    }
#pragma unroll
    for (int off = 32; off; off >>= 1) acc += __shfl_xor(acc, off, 64);
    __shared__ float red[4];
    if ((t & 63) == 0) red[t >> 6] = acc;
    __syncthreads();
    if (t == 0) v[col] = (red[0] + red[1]) + (red[2] + red[3]);
}

// ---------------------------------------------------------------------------
// K2: energies[s] = enc[s,:] . v   (the 128 MB pass — the whole problem)
// 1024 blocks x 256 threads (4 waves). Each wave handles 8 rows.
// Per row: 64 lanes x 4 float4 = full 1024-float row, coalesced.
// Software-pipelined: row r+1's loads issued before row r's reduce, so 8
// VMEM stay outstanding across the dependent shfl/expf chain.
// Online softmax stats (m, z) per block -> bstats[blockIdx].
// ---------------------------------------------------------------------------
__global__ void __launch_bounds__(256) k_energy(const float* __restrict__ enc,
                                                const float* __restrict__ v,
                                                float* __restrict__ energies,
                                                float2* __restrict__ bstats) {
    const int t = threadIdx.x;
    const int wave = t >> 6;
    const int lane = t & 63;
    const int row0 = (blockIdx.x << 5) + (wave << 3);

    const float4 vr0 = *reinterpret_cast<const float4*>(v +       (lane << 2));
    const float4 vr1 = *reinterpret_cast<const float4*>(v + 256 + (lane << 2));
    const float4 vr2 = *reinterpret_cast<const float4*>(v + 512 + (lane << 2));
    const float4 vr3 = *reinterpret_cast<const float4*>(v + 768 + (lane << 2));

    float m = -__builtin_inff();
    float z = 0.f;

    const float4* p = reinterpret_cast<const float4*>(enc + (size_t)row0 * HID) + lane;
    float4 a = p[0], b = p[64], c = p[128], d = p[192];

#pragma unroll
    for (int r = 0; r < 8; ++r) {
        float4 na, nb, nc, nd;
        if (r < 7) {
            const float4* q = p + (size_t)(r + 1) * 256;
            na = q[0]; nb = q[64]; nc = q[128]; nd = q[192];
        }
        float acc = a.x * vr0.x + a.y * vr0.y + a.z * vr0.z + a.w * vr0.w
                  + b.x * vr1.x + b.y * vr1.y + b.z * vr1.z + b.w * vr1.w
                  + c.x * vr2.x + c.y * vr2.y + c.z * vr2.z + c.w * vr2.w
                  + d.x * vr3.x + d.y * vr3.y + d.z * vr3.z + d.w * vr3.w;
#pragma unroll
        for (int off = 32; off; off >>= 1) acc += __shfl_xor(acc, off, 64);
        if (lane == 0) energies[row0 + r] = acc;
        const float nm = fmaxf(m, acc);
        z = z * __expf(m - nm) + __expf(acc - nm);
        m = nm;
        a = na; b = nb; c = nc; d = nd;
    }

    __shared__ float wm[4], wz[4];
    if (lane == 0) { wm[wave] = m; wz[wave] = z; }
    __syncthreads();
    if (t == 0) {
        float M = fmaxf(fmaxf(wm[0], wm[1]), fmaxf(wm[2], wm[3]));
        float Z = wz[0] * __expf(wm[0] - M) + wz[1] * __expf(wm[1] - M)
                + wz[2] * __expf(wm[2] - M) + wz[3] * __expf(wm[3] - M);
        bstats[blockIdx.x] = make_float2(M, Z);
    }
}

// ---------------------------------------------------------------------------
// K3: reduce 1024 block stats -> (M, Z) redundantly per block (8 KB, L2-hot),
// then write attn[i] = exp(e[i]-M)/Z. 64 blocks x 256 threads x 2 floats.
// ---------------------------------------------------------------------------
__global__ void __launch_bounds__(256) k_final(const float* __restrict__ energies,
                                               const float2* __restrict__ bstats,
                                               float* __restrict__ out) {
    __shared__ float sm[256], sz[256];
    const int t = threadIdx.x;
    float m = -__builtin_inff();
    float z = 0.f;
#pragma unroll
    for (int i = 0; i < 4; ++i) {
        const float2 s = bstats[t + (i << 8)];
        const float nm = fmaxf(m, s.x);
        z = z * __expf(m - nm) + s.y * __expf(s.x - nm);
        m = nm;
    }
    sm[t] = m; sz[t] = z;
    __syncthreads();
    for (int off = 128; off; off >>= 1) {
        if (t < off) {
            const float m1 = sm[t], z1 = sz[t];
            const float m2 = sm[t + off], z2 = sz[t + off];
            const float M = fmaxf(m1, m2);
            sm[t] = M;
            sz[t] = z1 * __expf(m1 - M) + z2 * __expf(m2 - M);
        }
        __syncthreads();
    }
    const float M = sm[0];
    const float rZ = 1.f / sz[0];

    const size_t i = ((size_t)blockIdx.x << 9) + ((size_t)t << 1);
    const float2 e = *reinterpret_cast<const float2*>(energies + i);
    float2 o;
    o.x = __expf(e.x - M) * rZ;
    o.y = __expf(e.y - M) * rZ;
    *reinterpret_cast<float2*>(out + i) = o;
}

extern "C" void kernel_launch(void* const* d_in, const int* in_sizes, int n_in,
                              void* d_out, int out_size, void* d_ws, size_t ws_size,
                              hipStream_t stream) {
    const float* hidden = (const float*)d_in[0];   // [1,1,1024]
    const float* enc    = (const float*)d_in[1];   // [32768,1024]
    const float* W      = (const float*)d_in[2];   // [1024,1024]
    // d_in[3] (bias) cancels in softmax (constant shift) — never read.

    float* ws       = (float*)d_ws;
    float* v        = ws;                            // 1024 floats
    float* energies = ws + HID;                      // 32768 floats
    float2* bstats  = (float2*)(ws + HID + SEQ_LEN); // 1024 float2

    k_matvec<<<HID, 256, 0, stream>>>(W, hidden, v);
    k_energy<<<SEQ_LEN / 32, 256, 0, stream>>>(enc, v, energies, bstats);
    k_final<<<SEQ_LEN / 512, 256, 0, stream>>>(energies, bstats, (float*)d_out);
}